// Round 1
// 523.111 us; speedup vs baseline: 1.0495x; 1.0495x over previous
//
#include <hip/hip_runtime.h>

#define BB 1024
#define TT 512
#define KK 64

// beta history: beta_t[j] = max_i(v_{t-1}[i] + T[i][j]) for t=1..511, stored
// PRE-emission and PRE-mask. 1024*511*64*4 B = 134 MB static device BSS --
// avoids any dependence on ws_size, no hipMalloc (graph-capture safe).
__device__ float g_bhist[BB * (TT - 1) * KK];

// ---- wave(64)-wide reductions via butterfly shuffles (epilogues only) ----
__device__ __forceinline__ float wmaxf(float x) {
#pragma unroll
  for (int off = 32; off > 0; off >>= 1) x = fmaxf(x, __shfl_xor(x, off, 64));
  return x;
}
__device__ __forceinline__ float wsumf(float x) {
#pragma unroll
  for (int off = 32; off > 0; off >>= 1) x += __shfl_xor(x, off, 64);
  return x;
}
__device__ __forceinline__ int wsumi(int x) {
#pragma unroll
  for (int off = 32; off > 0; off >>= 1) x += __shfl_xor(x, off, 64);
  return x;
}

// One block = one batch element. 128 threads = 2 waves:
//   wave0: forward algorithm (logZ) + gold score -> nll = logZ - gold
//   wave1: max-only viterbi recurrence (beta streamed to HBM) + equality
//          backtrace (ballot/ffs recovers argmax-first-index lazily).
// R5 redesign rationale (rocprof: VALUBusy 76%, HBM 3%, issue-bound): the
// per-step argmax index tracking (cmp+2*cndmask per element, ~150 instr/step)
// is dead weight during the forward pass -- only ONE column per step is ever
// consulted by the backtrace. So forward keeps max-only (v_max3-fused), and
// the backtrace recomputes the single needed column and finds the first lane
// whose score bitwise-equals the stored max (exact: same operands, same fp
// add order => bitwise-identical values; ballot+ffs == np.argmax tie-break).
extern "C" __global__ void __launch_bounds__(128) crf_all_kernel(
    const float* __restrict__ em,      // [B,T,K]
    const int* __restrict__ tags,      // [B,T]
    const int* __restrict__ mask,      // [B,T]
    const float* __restrict__ trans,   // [K,K]
    const float* __restrict__ startt,  // [K]
    const float* __restrict__ endt,    // [K]
    float* __restrict__ out) {         // [B] nll ++ [B,T] path (as float)
  __shared__ float Tp[KK * KK];                   // T'[j][i] = trans[i][j], 16 KB
  __shared__ __align__(16) float pbuf[KK];        // forward exp(alpha-M)
  __shared__ __align__(16) float vbuf[KK];        // viterbi v broadcast

  const int b = blockIdx.x;
  const int lane = threadIdx.x & 63;
  const float* emb = em + (size_t)b * TT * KK;
  const int* maskb = mask + b * TT;
  const int* tagsb = tags + b * TT;

  if (threadIdx.x < 64) {
    // ---------------- wave0: forward (logZ) + gold score ----------------
    float Ecol[KK];  // lane j holds column j of E = exp(trans)
#pragma unroll
    for (int i = 0; i < KK; ++i) Ecol[i] = __expf(trans[i * KK + lane]);

    float alpha = startt[lane] + emb[lane];
    for (int t = 1; t < TT; ++t) {
      float emv = emb[t * KK + lane];  // coalesced, issued early
      int m = maskb[t];
      // Stabilization point: ANY in-range M works (tolerance ~49 abs);
      // readfirstlane replaces the 6-deep ds_swizzle butterfly (absmax 0.0
      // with this across all prior rounds).
      float M = __int_as_float(__builtin_amdgcn_readfirstlane(__float_as_int(alpha)));
      pbuf[lane] = __expf(alpha - M);
      __builtin_amdgcn_wave_barrier();  // same-wave LDS in-order; fence compiler
      float s0 = 0.f, s1 = 0.f, s2 = 0.f, s3 = 0.f;
#pragma unroll
      for (int i = 0; i < KK; i += 4) {
        float4 pv = *(const float4*)&pbuf[i];  // same-address broadcast ds_read_b128
        s0 = fmaf(pv.x, Ecol[i + 0], s0);
        s1 = fmaf(pv.y, Ecol[i + 1], s1);
        s2 = fmaf(pv.z, Ecol[i + 2], s2);
        s3 = fmaf(pv.w, Ecol[i + 3], s3);
      }
      __builtin_amdgcn_wave_barrier();
      float na = __logf((s0 + s1) + (s2 + s3)) + M + emv;
      alpha = (m != 0) ? na : alpha;
    }
    // logZ = logsumexp(alpha + end) — exact max (runs once)
    float x = alpha + endt[lane];
    float M2 = wmaxf(x);
    float S = wsumf(__expf(x - M2));
    float logZ = __logf(S) + M2;

    // gold score: lane j covers t = u*64 + j
    float acc = 0.f;
    int msum = 0;
#pragma unroll
    for (int u = 0; u < TT / KK; ++u) {
      int t2 = u * KK + lane;
      int tg = tagsb[t2];
      int m = maskb[t2];
      msum += m;
      float mf = (float)m;
      acc = fmaf(emb[(size_t)t2 * KK + tg], mf, acc);
      if (t2 >= 1) acc = fmaf(trans[tagsb[t2 - 1] * KK + tg], mf, acc);
    }
    acc = wsumf(acc);
    msum = wsumi(msum);
    if (lane == 0) {
      float gold = acc + startt[tagsb[0]] + endt[tagsb[msum - 1]];
      out[b] = logZ - gold;
    }
  } else {
    // ---------------- wave1: max-only viterbi + equality backtrace --------
    float Tcol[KK];  // lane j holds column j of trans
#pragma unroll
    for (int i = 0; i < KK; ++i) Tcol[i] = trans[i * KK + lane];
    // Populate T'[j][i] = trans[i][j]: lane j owns row j of Tp (one-time;
    // write-side conflicts are a one-off cost, read side is conflict-free:
    // addr = tag*64 + lane -> banks stride-1 across lanes).
#pragma unroll
    for (int i = 0; i < KK; i += 4) {
      *(float4*)&Tp[lane * KK + i] =
          make_float4(Tcol[i], Tcol[i + 1], Tcol[i + 2], Tcol[i + 3]);
    }
    __builtin_amdgcn_wave_barrier();

    float* bh = g_bhist + (size_t)b * (TT - 1) * KK;
    float v = startt[lane] + emb[lane];
    for (int t = 1; t < TT; ++t) {
      float emv = emb[t * KK + lane];
      int m = maskb[t];
      vbuf[lane] = v;
      __builtin_amdgcn_wave_barrier();
      // Max-only: two interleaved accumulators, fmaxf(fmaxf(b,A),B) fuses to
      // v_max3_f32. No index tracking (recovered at backtrace).
      float bA = -3.402823466e38f, bB = -3.402823466e38f;
#pragma unroll
      for (int i = 0; i < KK; i += 8) {
        float4 lo = *(const float4*)&vbuf[i];       // broadcast ds_read_b128
        float4 hi = *(const float4*)&vbuf[i + 4];   // broadcast ds_read_b128
        float l0 = lo.x + Tcol[i + 0];
        float l1 = lo.y + Tcol[i + 1];
        float l2 = lo.z + Tcol[i + 2];
        float l3 = lo.w + Tcol[i + 3];
        float h0 = hi.x + Tcol[i + 4];
        float h1 = hi.y + Tcol[i + 5];
        float h2 = hi.z + Tcol[i + 6];
        float h3 = hi.w + Tcol[i + 7];
        bA = fmaxf(fmaxf(bA, fmaxf(l0, l1)), fmaxf(l2, l3));
        bB = fmaxf(fmaxf(bB, fmaxf(h0, h1)), fmaxf(h2, h3));
      }
      float best = fmaxf(bA, bB);
      __builtin_amdgcn_wave_barrier();
      bh[(size_t)(t - 1) * KK + lane] = best;  // coalesced 256B/step stream-out
      v = (m != 0) ? (best + emv) : v;
    }
    // last = argmax(v + end), first-index on exact ties (runs once)
    float sc = v + endt[lane];
    int idx = lane;
#pragma unroll
    for (int off = 32; off > 0; off >>= 1) {
      float osc = __shfl_xor(sc, off, 64);
      int oidx = __shfl_xor(idx, off, 64);
      if (osc > sc || (osc == sc && oidx < idx)) { sc = osc; idx = oidx; }
    }
    // ---- equality backtrace ----
    // Step tt (tag known): scalar beta_tt[tag] = bh[tt-1][tag] via shfl;
    // vector v_{tt-1}[i] = bh[tt-2][i] + em[tt-1][i] (bitwise == forward's v,
    // same operands & add order; mask is all-ones in this workload -- masked
    // steps keep tag unchanged via the m check below, matching bp=identity).
    // score[i] = v[i] + T'[tag][i]; first lane with score==beta is np.argmax.
    // Rows are tag-independent -> chunk-prefetch 8 steps of history.
    int tag = idx;
    float* pout = out + BB + (size_t)b * TT;
    int tt = TT - 1;
    while (tt >= 9) {  // process tt .. tt-7 (vector row needs bh[tt-9] >= bh[0])
      float Brow[9], Erow[8];
      int Mrow[8];
#pragma unroll
      for (int k = 0; k < 9; ++k) Brow[k] = bh[(size_t)(tt - 1 - k) * KK + lane];
#pragma unroll
      for (int k = 0; k < 8; ++k) Erow[k] = emb[(size_t)(tt - 1 - k) * KK + lane];
#pragma unroll
      for (int k = 0; k < 8; ++k) Mrow[k] = maskb[tt - k];
#pragma unroll
      for (int k = 0; k < 8; ++k) {
        if (lane == 0) pout[tt - k] = (float)tag;
        float beta = __shfl(Brow[k], tag, 64);
        float sc2 = (Brow[k + 1] + Erow[k]) + Tp[tag * KK + lane];
        unsigned long long mm = __ballot(sc2 == beta);
        int nt = (int)__ffsll(mm) - 1;
        tag = (Mrow[k] != 0) ? nt : tag;
      }
      tt -= 8;
    }
    for (; tt >= 2; --tt) {
      if (lane == 0) pout[tt] = (float)tag;
      float beta = __shfl(bh[(size_t)(tt - 1) * KK + lane], tag, 64);
      float sc2 = (bh[(size_t)(tt - 2) * KK + lane] + emb[(size_t)(tt - 1) * KK + lane]) +
                  Tp[tag * KK + lane];
      unsigned long long mm = __ballot(sc2 == beta);
      int nt = (int)__ffsll(mm) - 1;
      tag = (maskb[tt] != 0) ? nt : tag;
    }
    {  // tt == 1: vector row is v_0 = start + em[0] (bitwise == forward init)
      if (lane == 0) pout[1] = (float)tag;
      float beta = __shfl(bh[lane], tag, 64);
      float sc2 = (startt[lane] + emb[lane]) + Tp[tag * KK + lane];
      unsigned long long mm = __ballot(sc2 == beta);
      int nt = (int)__ffsll(mm) - 1;
      tag = (maskb[1] != 0) ? nt : tag;
      if (lane == 0) pout[0] = (float)tag;
    }
  }
}

extern "C" void kernel_launch(void* const* d_in, const int* in_sizes, int n_in,
                              void* d_out, int out_size, void* d_ws, size_t ws_size,
                              hipStream_t stream) {
  (void)in_sizes; (void)n_in; (void)out_size; (void)d_ws; (void)ws_size;
  const float* em = (const float*)d_in[0];
  const int* tags = (const int*)d_in[1];
  const int* mask = (const int*)d_in[2];
  const float* trans = (const float*)d_in[3];
  const float* startt = (const float*)d_in[4];
  const float* endt = (const float*)d_in[5];
  float* out = (float*)d_out;
  crf_all_kernel<<<dim3(BB), dim3(128), 0, stream>>>(em, tags, mask, trans,
                                                     startt, endt, out);
}

// Round 2
// 424.306 us; speedup vs baseline: 1.2939x; 1.2329x over previous
//
#include <hip/hip_runtime.h>

#define BB 1024
#define TT 512
#define KK 64

// beta history: beta_t[j] = max_i(v_{t-1}[i] + T[i][j]) for t=1..511, stored
// PRE-emission and PRE-mask. 1024*511*64*4 B = 134 MB static device BSS.
__device__ float g_bhist[BB * (TT - 1) * KK];

// ---- wave(64)-wide reductions via butterfly shuffles (epilogues only) ----
__device__ __forceinline__ float wmaxf(float x) {
#pragma unroll
  for (int off = 32; off > 0; off >>= 1) x = fmaxf(x, __shfl_xor(x, off, 64));
  return x;
}
__device__ __forceinline__ float wsumf(float x) {
#pragma unroll
  for (int off = 32; off > 0; off >>= 1) x += __shfl_xor(x, off, 64);
  return x;
}
__device__ __forceinline__ int wsumi(int x) {
#pragma unroll
  for (int off = 32; off > 0; off >>= 1) x += __shfl_xor(x, off, 64);
  return x;
}

// One block = one batch element. 128 threads = 2 waves:
//   wave0: forward algorithm (logZ) + gold score -> nll = logZ - gold
//   wave1: max-only viterbi recurrence (beta streamed to HBM) + equality
//          backtrace (ballot/ffs recovers argmax-first-index lazily).
// R2 rationale: R1's VGPR_Count=52 proves Ecol[64]/Tcol[64] were never
// register-resident -- the allocator replayed the tables through the memory
// pipe every step (invisible in FETCH_SIZE: 16 KB table is L1-resident).
// __launch_bounds__(128,2) relaxes the occupancy target so the tables fit in
// VGPRs (grid supplies only 2 waves/SIMD regardless). Explicit depth-8 em
// prefetch rings take HBM latency off the serial chain; mask row staged in
// LDS once. All arithmetic orderings are identical to R1 (absmax 0.0).
extern "C" __global__ void __launch_bounds__(128, 2) crf_all_kernel(
    const float* __restrict__ em,      // [B,T,K]
    const int* __restrict__ tags,      // [B,T]
    const int* __restrict__ mask,      // [B,T]
    const float* __restrict__ trans,   // [K,K]
    const float* __restrict__ startt,  // [K]
    const float* __restrict__ endt,    // [K]
    float* __restrict__ out) {         // [B] nll ++ [B,T] path (as float)
  __shared__ float Tp[KK * KK];                   // T'[j][i] = trans[i][j], 16 KB
  __shared__ int msk[TT];                         // mask row, 2 KB
  __shared__ __align__(16) float pbuf[KK];        // forward exp(alpha-M)
  __shared__ __align__(16) float vbuf[KK];        // viterbi v broadcast

  const int b = blockIdx.x;
  const int lane = threadIdx.x & 63;
  const float* emb = em + (size_t)b * TT * KK;
  const int* maskb = mask + b * TT;
  const int* tagsb = tags + b * TT;

  // Stage mask row into LDS. Both waves write identical values (benign race,
  // aligned dwords); each wave's own writes are ordered before its reads.
#pragma unroll
  for (int u = 0; u < TT / KK; ++u) msk[u * KK + lane] = maskb[u * KK + lane];
  __builtin_amdgcn_wave_barrier();

  if (threadIdx.x < 64) {
    // ---------------- wave0: forward (logZ) + gold score ----------------
    float Ecol[KK];  // lane j holds column j of E = exp(trans)
#pragma unroll
    for (int i = 0; i < KK; ++i) Ecol[i] = __expf(trans[i * KK + lane]);

    float alpha = startt[lane] + emb[lane];

    auto fwd_step = [&](int t, float emv) {
      int m = msk[t];
      // Stabilization point: ANY in-range M works; readfirstlane replaces a
      // butterfly (absmax 0.0 across all prior rounds with this).
      float M = __int_as_float(__builtin_amdgcn_readfirstlane(__float_as_int(alpha)));
      pbuf[lane] = __expf(alpha - M);
      __builtin_amdgcn_wave_barrier();  // same-wave LDS in-order; fence compiler
      float s0 = 0.f, s1 = 0.f, s2 = 0.f, s3 = 0.f;
#pragma unroll
      for (int i = 0; i < KK; i += 4) {
        float4 pv = *(const float4*)&pbuf[i];  // same-address broadcast ds_read_b128
        s0 = fmaf(pv.x, Ecol[i + 0], s0);
        s1 = fmaf(pv.y, Ecol[i + 1], s1);
        s2 = fmaf(pv.z, Ecol[i + 2], s2);
        s3 = fmaf(pv.w, Ecol[i + 3], s3);
      }
      __builtin_amdgcn_wave_barrier();
      float na = __logf((s0 + s1) + (s2 + s3)) + M + emv;
      alpha = (m != 0) ? na : alpha;
    };

    // depth-8 register prefetch ring over t
    float er[8];
#pragma unroll
    for (int k = 0; k < 8; ++k) er[k] = emb[(size_t)(1 + k) * KK + lane];
    for (int tb = 1; tb <= TT - 15; tb += 8) {  // t = 1 .. 504
#pragma unroll
      for (int k = 0; k < 8; ++k) {
        int t = tb + k;
        float emv = er[k];
        int tp = t + 8;
        tp = (tp < TT) ? tp : (TT - 1);  // clamped (redundant loads harmless)
        er[k] = emb[(size_t)tp * KK + lane];
        fwd_step(t, emv);
      }
    }
#pragma unroll
    for (int k = 0; k < 7; ++k) {  // t = 505 .. 511, ring slots 0..6
      fwd_step(TT - 7 + k, er[k]);
    }

    // logZ = logsumexp(alpha + end) — exact max (runs once)
    float x = alpha + endt[lane];
    float M2 = wmaxf(x);
    float S = wsumf(__expf(x - M2));
    float logZ = __logf(S) + M2;

    // gold score: lane j covers t = u*64 + j
    float acc = 0.f;
    int msum = 0;
#pragma unroll
    for (int u = 0; u < TT / KK; ++u) {
      int t2 = u * KK + lane;
      int tg = tagsb[t2];
      int m = msk[t2];
      msum += m;
      float mf = (float)m;
      acc = fmaf(emb[(size_t)t2 * KK + tg], mf, acc);
      if (t2 >= 1) acc = fmaf(trans[tagsb[t2 - 1] * KK + tg], mf, acc);
    }
    acc = wsumf(acc);
    msum = wsumi(msum);
    if (lane == 0) {
      float gold = acc + startt[tagsb[0]] + endt[tagsb[msum - 1]];
      out[b] = logZ - gold;
    }
  } else {
    // ---------------- wave1: max-only viterbi + equality backtrace --------
    float Tcol[KK];  // lane j holds column j of trans
#pragma unroll
    for (int i = 0; i < KK; ++i) Tcol[i] = trans[i * KK + lane];
    // Populate T'[j][i] = trans[i][j]: lane j owns row j of Tp (one-time;
    // write-side conflicts are a one-off cost; read side conflict-free).
#pragma unroll
    for (int i = 0; i < KK; i += 4) {
      *(float4*)&Tp[lane * KK + i] =
          make_float4(Tcol[i], Tcol[i + 1], Tcol[i + 2], Tcol[i + 3]);
    }
    __builtin_amdgcn_wave_barrier();

    float* bh = g_bhist + (size_t)b * (TT - 1) * KK;
    float v = startt[lane] + emb[lane];

    auto vit_step = [&](int t, float emv) {
      int m = msk[t];
      vbuf[lane] = v;
      __builtin_amdgcn_wave_barrier();
      // Max-only: two interleaved accumulators, fmaxf(fmaxf(b,A),B) fuses to
      // v_max3_f32. No index tracking (recovered at backtrace).
      float bA = -3.402823466e38f, bB = -3.402823466e38f;
#pragma unroll
      for (int i = 0; i < KK; i += 8) {
        float4 lo = *(const float4*)&vbuf[i];      // broadcast ds_read_b128
        float4 hi = *(const float4*)&vbuf[i + 4];  // broadcast ds_read_b128
        float l0 = lo.x + Tcol[i + 0];
        float l1 = lo.y + Tcol[i + 1];
        float l2 = lo.z + Tcol[i + 2];
        float l3 = lo.w + Tcol[i + 3];
        float h0 = hi.x + Tcol[i + 4];
        float h1 = hi.y + Tcol[i + 5];
        float h2 = hi.z + Tcol[i + 6];
        float h3 = hi.w + Tcol[i + 7];
        bA = fmaxf(fmaxf(bA, fmaxf(l0, l1)), fmaxf(l2, l3));
        bB = fmaxf(fmaxf(bB, fmaxf(h0, h1)), fmaxf(h2, h3));
      }
      float best = fmaxf(bA, bB);
      __builtin_amdgcn_wave_barrier();
      bh[(size_t)(t - 1) * KK + lane] = best;  // coalesced 256B/step stream-out
      v = (m != 0) ? (best + emv) : v;
    };

    // depth-8 register prefetch ring over t
    float er[8];
#pragma unroll
    for (int k = 0; k < 8; ++k) er[k] = emb[(size_t)(1 + k) * KK + lane];
    for (int tb = 1; tb <= TT - 15; tb += 8) {  // t = 1 .. 504
#pragma unroll
      for (int k = 0; k < 8; ++k) {
        int t = tb + k;
        float emv = er[k];
        int tp = t + 8;
        tp = (tp < TT) ? tp : (TT - 1);
        er[k] = emb[(size_t)tp * KK + lane];
        vit_step(t, emv);
      }
    }
#pragma unroll
    for (int k = 0; k < 7; ++k) {  // t = 505 .. 511
      vit_step(TT - 7 + k, er[k]);
    }

    // last = argmax(v + end), first-index on exact ties (runs once)
    float sc = v + endt[lane];
    int idx = lane;
#pragma unroll
    for (int off = 32; off > 0; off >>= 1) {
      float osc = __shfl_xor(sc, off, 64);
      int oidx = __shfl_xor(idx, off, 64);
      if (osc > sc || (osc == sc && oidx < idx)) { sc = osc; idx = oidx; }
    }
    // ---- equality backtrace ----
    // Step tt (tag known): scalar beta_tt[tag] = bh[tt-1][tag] via shfl;
    // vector v_{tt-1}[i] = bh[tt-2][i] + em[tt-1][i] (bitwise == forward's v,
    // same operands & add order). score[i] = v[i] + T'[tag][i]; first lane
    // with score==beta is np.argmax. History rows are tag-independent ->
    // chunk-prefetch 8 steps.
    int tag = idx;
    float* pout = out + BB + (size_t)b * TT;
    int tt = TT - 1;
    while (tt >= 9) {  // process tt .. tt-7
      float Brow[9], Erow[8];
      int Mrow[8];
#pragma unroll
      for (int k = 0; k < 9; ++k) Brow[k] = bh[(size_t)(tt - 1 - k) * KK + lane];
#pragma unroll
      for (int k = 0; k < 8; ++k) Erow[k] = emb[(size_t)(tt - 1 - k) * KK + lane];
#pragma unroll
      for (int k = 0; k < 8; ++k) Mrow[k] = msk[tt - k];
#pragma unroll
      for (int k = 0; k < 8; ++k) {
        if (lane == 0) pout[tt - k] = (float)tag;
        float beta = __shfl(Brow[k], tag, 64);
        float sc2 = (Brow[k + 1] + Erow[k]) + Tp[tag * KK + lane];
        unsigned long long mm = __ballot(sc2 == beta);
        int nt = (int)__ffsll(mm) - 1;
        tag = (Mrow[k] != 0) ? nt : tag;
      }
      tt -= 8;
    }
    for (; tt >= 2; --tt) {
      if (lane == 0) pout[tt] = (float)tag;
      float beta = __shfl(bh[(size_t)(tt - 1) * KK + lane], tag, 64);
      float sc2 = (bh[(size_t)(tt - 2) * KK + lane] + emb[(size_t)(tt - 1) * KK + lane]) +
                  Tp[tag * KK + lane];
      unsigned long long mm = __ballot(sc2 == beta);
      int nt = (int)__ffsll(mm) - 1;
      tag = (msk[tt] != 0) ? nt : tag;
    }
    {  // tt == 1: vector row is v_0 = start + em[0] (bitwise == forward init)
      if (lane == 0) pout[1] = (float)tag;
      float beta = __shfl(bh[lane], tag, 64);
      float sc2 = (startt[lane] + emb[lane]) + Tp[tag * KK + lane];
      unsigned long long mm = __ballot(sc2 == beta);
      int nt = (int)__ffsll(mm) - 1;
      tag = (msk[1] != 0) ? nt : tag;
      if (lane == 0) pout[0] = (float)tag;
    }
  }
}

extern "C" void kernel_launch(void* const* d_in, const int* in_sizes, int n_in,
                              void* d_out, int out_size, void* d_ws, size_t ws_size,
                              hipStream_t stream) {
  (void)in_sizes; (void)n_in; (void)out_size; (void)d_ws; (void)ws_size;
  const float* em = (const float*)d_in[0];
  const int* tags = (const int*)d_in[1];
  const int* mask = (const int*)d_in[2];
  const float* trans = (const float*)d_in[3];
  const float* startt = (const float*)d_in[4];
  const float* endt = (const float*)d_in[5];
  float* out = (float*)d_out;
  crf_all_kernel<<<dim3(BB), dim3(128), 0, stream>>>(em, tags, mask, trans,
                                                     startt, endt, out);
}